// Round 8
// baseline (360.816 us; speedup 1.0000x reference)
//
#include <hip/hip_runtime.h>

// Problem constants (B=1)
constexpr int kN1 = 512;
constexpr int kN2 = 2048;
constexpr int kC  = 1024;
constexpr int kHD = 128;
constexpr int kC2 = 2048;
constexpr int kC3 = 3072;

typedef _Float16 half8 __attribute__((ext_vector_type(8)));
typedef _Float16 half4v __attribute__((ext_vector_type(4)));
typedef float f32x4 __attribute__((ext_vector_type(4)));

// async global->LDS, 16 B per lane; LDS dest is wave-uniform base + lane*16
#define GLD16(gptr, lptr) \
    __builtin_amdgcn_global_load_lds((const __attribute__((address_space(1))) void*)(gptr), \
                                     (__attribute__((address_space(3))) void*)(lptr), 16, 0, 0)

// s_waitcnt immediates: vmcnt [3:0]|[15:14], expcnt [6:4], lgkmcnt [11:8]
#define WAIT_VM4   0x0F74  // vmcnt(4)
#define WAIT_VM0   0x0F70  // vmcnt(0)
#define WAIT_LGKM0 0xC07F  // lgkmcnt(0)

// ---------------------------------------------------------------------------
// GEMM descriptor: runtime-parameterized NT MFMA GEMM so two independent
// GEMMs can share one launch (block picks its descriptor by blockIdx.z).
// zz = bz / SK; s = bz % SK; h = ahx ? blockIdx.x : zz & hmask;
// g = ahx ? zz : zz >> hshift.
// A += h*sAh + g*sAg; B += h*sBh + g*sBg; Coff = s*sSplit + h*sCh + g*sCg.
// ---------------------------------------------------------------------------
struct GD {
    const _Float16* A; const _Float16* B; void* C;
    const float* colScale;
    long sAh, sAg, sBh, sBg, sSplit, sCh, sCg;
    int lda, ldb, ldc, K, SK, hmask, hshift;
    int ahx, outHalf, csMode, nx, ny;     // csMode: 0 none, 1 always, 2 g==0
    float alpha;
};

// Tile 128x128, BK=32, 256 threads (4 waves, 64x64 each), 32 KB LDS dbuf.
__global__ __launch_bounds__(256)
void hgemm2(GD d0, GD d1, int zSplit)
{
    const bool second = (int)blockIdx.z >= zSplit;
    const GD& d = second ? d1 : d0;
    const int bz = second ? (int)blockIdx.z - zSplit : (int)blockIdx.z;
    if ((int)blockIdx.x >= d.nx || (int)blockIdx.y >= d.ny) return;

    __shared__ uint4 smem[2048];          // 32 KB: 2 x (A 8 KB | B 8 KB)
    char* smembase = (char*)smem;
    const int tid = threadIdx.x;
    const int w = tid >> 6, l = tid & 63;
    const int m0 = blockIdx.y << 7, n0 = blockIdx.x << 7;
    const int wm = (w >> 1) << 6, wn = (w & 1) << 6;
    const int kq = l >> 4, lm = l & 15;

    const int zz = bz / d.SK, s = bz - zz * d.SK;
    const int h = d.ahx ? (int)blockIdx.x : (zz & d.hmask);
    const int g = d.ahx ? zz : (zz >> d.hshift);
    const _Float16* A = d.A + (long)h * d.sAh + (long)g * d.sAg;
    const _Float16* B = d.B + (long)h * d.sBh + (long)g * d.sBg;
    const long Coff = (long)s * d.sSplit + (long)h * d.sCh + (long)g * d.sCg;
    const int kper = d.K / d.SK, kbeg = s * kper;
    const int nIter = kper >> 5;

    const int skq = w >> 1;
    const int sr0 = (w & 1) << 6;
    const _Float16* gA = A + (long)(m0 + sr0 + l) * d.lda + skq * 8 + kbeg;
    const _Float16* gB = B + (long)(n0 + sr0 + l) * d.ldb + skq * 8 + kbeg;
    const int soff = skq * 2048 + (sr0 + l) * 16;

    auto stage = [&](int it, int b) {
        char* dst = smembase + b * 16384;
        const int k0 = it << 5;
        GLD16(gA + k0,      dst + soff);
        GLD16(gA + k0 + 16, dst + soff + 4096);
        GLD16(gB + k0,      dst + 8192 + soff);
        GLD16(gB + k0 + 16, dst + 8192 + soff + 4096);
    };

    f32x4 acc[4][4] = {};
    stage(0, 0);

    for (int it = 0; it < nIter; ++it) {
        const int cur = it & 1;
        if (it + 1 < nIter) {
            stage(it + 1, cur ^ 1);
            __builtin_amdgcn_s_waitcnt(WAIT_VM4);   // tile-it's 4 loads done
        } else {
            __builtin_amdgcn_s_waitcnt(WAIT_VM0);
        }
        __builtin_amdgcn_s_barrier();               // all waves' loads landed
        const char* cbase = smembase + cur * 16384;
        half8 af[4], bfr[4];
        const char* pa = cbase + kq * 2048 + (wm + lm) * 16;
        const char* pb = cbase + 8192 + kq * 2048 + (wn + lm) * 16;
        #pragma unroll
        for (int i = 0; i < 4; ++i) {
            af[i]  = *(const half8*)(pa + i * 256);
            bfr[i] = *(const half8*)(pb + i * 256);
        }
        #pragma unroll
        for (int mi = 0; mi < 4; ++mi)
            #pragma unroll
            for (int ni = 0; ni < 4; ++ni)
                acc[mi][ni] = __builtin_amdgcn_mfma_f32_16x16x32_f16(af[mi], bfr[ni], acc[mi][ni], 0, 0, 0);
        __builtin_amdgcn_s_waitcnt(WAIT_LGKM0);     // own ds_reads retired
        __builtin_amdgcn_s_barrier();               // all done reading cur
    }

    // C/D layout: col = lane&15, row = (lane>>4)*4 + reg
    const int rbase = m0 + wm + kq * 4;
    #pragma unroll
    for (int mi = 0; mi < 4; ++mi) {
        #pragma unroll
        for (int ni = 0; ni < 4; ++ni) {
            const int col = n0 + wn + ni * 16 + lm;
            float cs = d.alpha;
            if (d.csMode == 1 || (d.csMode == 2 && g == 0)) cs *= d.colScale[col];
            #pragma unroll
            for (int r = 0; r < 4; ++r) {
                const long row = rbase + mi * 16 + r;
                const float v = acc[mi][ni][r] * cs;
                const long off = Coff + row * d.ldc + col;
                if (d.outHalf) ((_Float16*)d.C)[off] = (_Float16)v;
                else           ((float*)d.C)[off] = v;
            }
        }
    }
}

static GD mkgd(const _Float16* A, const _Float16* B, void* C, const float* cscale,
               long sAh, long sAg, long sBh, long sBg, long sSplit, long sCh, long sCg,
               int lda, int ldb, int ldc, int K, int SK, int hmask, int hshift,
               int ahx, int outHalf, int csMode, int nx, int ny, float alpha)
{
    GD d; d.A=A; d.B=B; d.C=C; d.colScale=cscale;
    d.sAh=sAh; d.sAg=sAg; d.sBh=sBh; d.sBg=sBg; d.sSplit=sSplit; d.sCh=sCh; d.sCg=sCg;
    d.lda=lda; d.ldb=ldb; d.ldc=ldc; d.K=K; d.SK=SK; d.hmask=hmask; d.hshift=hshift;
    d.ahx=ahx; d.outHalf=outHalf; d.csMode=csMode; d.nx=nx; d.ny=ny; d.alpha=alpha;
    return d;
}

// ---------------------------------------------------------------------------
// fp32 -> fp16 cast, z picks (x_cls | x_reg) -> d[z]
// ---------------------------------------------------------------------------
__global__ __launch_bounds__(256)
void cast_f2h(const float* __restrict__ s0, const float* __restrict__ s1,
              _Float16* __restrict__ d, int n4)
{
    const int i = blockIdx.x * 256 + threadIdx.x;
    const float* s = blockIdx.y ? s1 : s0;
    const float4 v = ((const float4*)s)[i];
    half4v o;
    o.x = (_Float16)v.x; o.y = (_Float16)v.y; o.z = (_Float16)v.z; o.w = (_Float16)v.w;
    ((half4v*)(d + (size_t)blockIdx.y * n4 * 4))[i] = o;
}

// ---------------------------------------------------------------------------
// All six weight transposes in one launch. Grid (64,64,6); idle blocks exit.
// dst[n][k] = src[k][n], fp32 -> fp16.
// ---------------------------------------------------------------------------
__global__ __launch_bounds__(256)
void prep_transpose(const float* __restrict__ Wq_c, const float* __restrict__ Wq_r,
                    const float* __restrict__ Wkv_c, const float* __restrict__ Wkv_r,
                    const float* __restrict__ Wl_c, const float* __restrict__ Wl_r,
                    _Float16* __restrict__ WqT, _Float16* __restrict__ WkvT,
                    _Float16* __restrict__ WlinT)
{
    __shared__ float t[32][33];
    const int z = blockIdx.z;
    const float* src; _Float16* dst; int ldsrc, lddst, nx, ky;
    switch (z) {
        case 0: src=Wq_c;  dst=WqT;            ldsrc=1024; lddst=1024; nx=32; ky=32; break;
        case 1: src=Wq_r;  dst=WqT+1048576;    ldsrc=1024; lddst=1024; nx=32; ky=32; break;
        case 2: src=Wkv_c; dst=WkvT;           ldsrc=2048; lddst=1024; nx=64; ky=32; break;
        case 3: src=Wkv_r; dst=WkvT+2097152;   ldsrc=2048; lddst=1024; nx=64; ky=32; break;
        case 4: src=Wl_c;  dst=WlinT;          ldsrc=2048; lddst=2048; nx=64; ky=64; break;
        default:src=Wl_r;  dst=WlinT+4194304;  ldsrc=2048; lddst=2048; nx=64; ky=64; break;
    }
    if ((int)blockIdx.x >= nx || (int)blockIdx.y >= ky) return;
    const int n0 = blockIdx.x << 5, k0 = blockIdx.y << 5;
    const int tx = threadIdx.x & 31, ty = threadIdx.x >> 5;
    #pragma unroll
    for (int j = ty; j < 32; j += 8)
        t[j][tx] = src[(size_t)(k0 + j) * ldsrc + n0 + tx];
    __syncthreads();
    #pragma unroll
    for (int j = ty; j < 32; j += 8)
        dst[(size_t)(n0 + j) * lddst + k0 + tx] = (_Float16)t[tx][j];
}

// ---------------------------------------------------------------------------
// V^T with inline 2-way split-K sum: vT[g][n][k] = sum_s kvpart[s][g][k][1024+n]
// Grid (32, 64, 2).
// ---------------------------------------------------------------------------
__global__ __launch_bounds__(256)
void vT_sum(const _Float16* __restrict__ kvpart, _Float16* __restrict__ vT)
{
    __shared__ float t[32][33];
    const int g = blockIdx.z;
    const int n0 = blockIdx.x << 5, k0 = blockIdx.y << 5;
    const int tx = threadIdx.x & 31, ty = threadIdx.x >> 5;
    const _Float16* s0 = kvpart + (size_t)g * 4194304 + 1024;
    #pragma unroll
    for (int j = ty; j < 32; j += 8) {
        const size_t o = (size_t)(k0 + j) * 2048 + n0 + tx;
        t[j][tx] = (float)s0[o] + (float)s0[8388608 + o];
    }
    __syncthreads();
    _Float16* d = vT + (size_t)g * 2097152;
    #pragma unroll
    for (int j = ty; j < 32; j += 8)
        d[(size_t)(n0 + j) * 2048 + k0 + tx] = (_Float16)t[tx][j];
}

// ---------------------------------------------------------------------------
// q-norm fused with 8-way split-K reduce. qpart16 [8][2][512][1024] fp16.
// ---------------------------------------------------------------------------
__global__ __launch_bounds__(256)
void headnorm_q(const _Float16* __restrict__ qpart, _Float16* __restrict__ qn)
{
    const int vid = blockIdx.x * 4 + (threadIdx.x >> 6);   // [0, 8192)
    const int lane = threadIdx.x & 63;
    const int g = vid >> 12, rr = vid & 4095, row = rr >> 3, hh = rr & 7;
    const size_t o = (size_t)g * 524288 + (size_t)row * 1024 + hh * 128 + lane * 2;
    float a = 0.f, b = 0.f;
    #pragma unroll
    for (int s = 0; s < 8; ++s) {
        a += (float)qpart[(size_t)s * 1048576 + o];
        b += (float)qpart[(size_t)s * 1048576 + o + 1];
    }
    float ss = a * a + b * b;
    #pragma unroll
    for (int d = 32; d > 0; d >>= 1) ss += __shfl_xor(ss, d, 64);
    const float inv = rsqrtf(ss);
    qn[o] = (_Float16)(a * inv); qn[o + 1] = (_Float16)(b * inv);
}

// ---------------------------------------------------------------------------
// kv-norm with inline 2-way split-K sum; also emits raw V rows<512 (x_ori).
// kvpart [2][2][2048][2048] fp16.
// ---------------------------------------------------------------------------
__global__ __launch_bounds__(256)
void headnorm_kv(const _Float16* __restrict__ kvpart,
                 _Float16* __restrict__ kn, _Float16* __restrict__ vn,
                 _Float16* __restrict__ x_ori)
{
    const int vid = blockIdx.x * 4 + (threadIdx.x >> 6);   // [0, 65536)
    const int lane = threadIdx.x & 63;
    const int half_ = vid >> 15;                // 0 = K, 1 = V
    const int r15 = vid & 32767;
    const int g = r15 >> 14, rr = r15 & 16383, row = rr >> 3, hh = rr & 7;
    const size_t so = (size_t)g * 4194304 + (size_t)row * 2048
                    + half_ * 1024 + hh * 128 + lane * 2;
    const float a = (float)kvpart[so] + (float)kvpart[8388608 + so];
    const float b = (float)kvpart[so + 1] + (float)kvpart[8388608 + so + 1];
    float ss = a * a + b * b;
    #pragma unroll
    for (int d = 32; d > 0; d >>= 1) ss += __shfl_xor(ss, d, 64);
    const float inv = rsqrtf(ss);
    const size_t dofs = (size_t)g * 2097152 + (size_t)row * 1024 + hh * 128 + lane * 2;
    _Float16* dp = (half_ ? vn : kn) + dofs;
    dp[0] = (_Float16)(a * inv); dp[1] = (_Float16)(b * inv);
    if (half_ == 1 && row < 512) {
        _Float16* xo = x_ori + (size_t)g * 524288 + (size_t)row * 1024 + hh * 128 + lane * 2;
        xo[0] = (_Float16)a; xo[1] = (_Float16)b;
    }
}

// ---------------------------------------------------------------------------
// Block reduce (256 threads, 4 waves). OP: 0 sum, 1 max
// ---------------------------------------------------------------------------
template<int OP>
__device__ __forceinline__ float bred(float v, float* lds)
{
    #pragma unroll
    for (int o = 32; o > 0; o >>= 1) {
        const float u = __shfl_xor(v, o, 64);
        v = OP ? fmaxf(v, u) : v + u;
    }
    __syncthreads();
    if ((threadIdx.x & 63) == 0) lds[threadIdx.x >> 6] = v;
    __syncthreads();
    return OP ? fmaxf(fmaxf(lds[0], lds[1]), fmaxf(lds[2], lds[3]))
              : lds[0] + lds[1] + lds[2] + lds[3];
}

// ---------------------------------------------------------------------------
// Fused: per q row — dual softmax per head + blend -> fp16 attn + head-mean,
// then round-2 masked renorm weights. v-sim 4-way split-K reduced inline.
// S16 [16][512][2048] fp16 (0-7 cls, 8-15 reg); simPart [4][2][512][2048] f32.
// ---------------------------------------------------------------------------
__global__ __launch_bounds__(256)
void sb2_kernel(const _Float16* __restrict__ S16, const float* __restrict__ simPart,
                _Float16* __restrict__ attn,
                _Float16* __restrict__ wc, _Float16* __restrict__ wr)
{
    __shared__ float lds[4];
    const int q = blockIdx.x, t = threadIdx.x;
    float asum[8] = {};
    for (int hh = 0; hh < 8; ++hh) {
        const size_t rb = (size_t)(hh * 512 + q) * 2048;
        float vc[8], vr[8];
        float mc = -1e30f, mr = -1e30f;
        #pragma unroll
        for (int j = 0; j < 8; ++j) {
            vc[j] = (float)S16[rb + t + 256 * j];
            vr[j] = (float)S16[8388608 + rb + t + 256 * j];
            mc = fmaxf(mc, vc[j]); mr = fmaxf(mr, vr[j]);
        }
        mc = bred<1>(mc, lds);
        mr = bred<1>(mr, lds);
        float sc = 0.f, sr = 0.f;
        #pragma unroll
        for (int j = 0; j < 8; ++j) {
            vc[j] = expf(vc[j] - mc); sc += vc[j];
            vr[j] = expf(vr[j] - mr); sr += vr[j];
        }
        sc = bred<0>(sc, lds);
        sr = bred<0>(sr, lds);
        const float ic = 0.5f / sc, ir = 0.5f / sr;
        #pragma unroll
        for (int j = 0; j < 8; ++j) {
            const float a = vc[j] * ic + vr[j] * ir;
            attn[rb + t + 256 * j] = (_Float16)a;
            asum[j] += a;
        }
    }
    float mx = -1e30f;
    #pragma unroll
    for (int j = 0; j < 8; ++j) { asum[j] *= 0.125f; mx = fmaxf(mx, asum[j]); }
    mx = bred<1>(mx, lds);
    float em[8], emo[8];
    float s1 = 0.f, s2 = 0.f;
    const size_t qb = (size_t)q * 2048;
    #pragma unroll
    for (int j = 0; j < 8; ++j) {
        const size_t o = qb + t + 256 * j;
        float sim = 0.f, reg = 0.f;
        #pragma unroll
        for (int s = 0; s < 4; ++s) {
            sim += simPart[(size_t)s * 2097152 + o];
            reg += simPart[(size_t)s * 2097152 + 1048576 + o];
        }
        const float e = expf(asum[j] - mx);
        const float m  = sim > 0.75f ? 1.f : 0.f;
        const float mo = reg > 0.99f ? 1.f : 0.f;
        em[j] = e * m; emo[j] = e * m * mo;
        s1 += em[j]; s2 += emo[j];
    }
    s1 = bred<0>(s1, lds);
    s2 = bred<0>(s2, lds);
    const float i1 = 1.f / s1, i2 = 1.f / s2;
    #pragma unroll
    for (int j = 0; j < 8; ++j) {
        wc[qb + t + 256 * j] = (_Float16)(em[j] * i1);
        wr[qb + t + 256 * j] = (_Float16)(emo[j] * i2);
    }
}

// ---------------------------------------------------------------------------
// xcat16 [2][512][2048]: cols<1024 = 8-way reduce of attn@V partials,
// cols>=1024 = x_ori (raw V rows<512).
// ---------------------------------------------------------------------------
__global__ __launch_bounds__(256)
void build_xcat(const float* __restrict__ xcatPart, const _Float16* __restrict__ x_ori,
                _Float16* __restrict__ xcat)
{
    const int idx = blockIdx.x * 256 + threadIdx.x;   // 2*512*2048
    const int j = idx & 2047;
    const int n = (idx >> 11) & 511;
    const int g = idx >> 20;
    _Float16 v;
    if (j < 1024) {
        float a = 0.f;
        #pragma unroll
        for (int s = 0; s < 8; ++s)
            a += xcatPart[(size_t)s * 1048576 + (size_t)g * 524288 + n * 1024 + j];
        v = (_Float16)a;
    } else {
        v = x_ori[(size_t)g * 524288 + (size_t)n * 1024 + (j - 1024)];
    }
    xcat[idx] = v;
}

// ---------------------------------------------------------------------------
// finalize d_out [2][512][3072]: cols<1024 8-way avePart reduce; cols>=1024
// 4-way outPart reduce + bias.
// ---------------------------------------------------------------------------
__global__ __launch_bounds__(256)
void finalize(const float* __restrict__ avePart, const float* __restrict__ outPart,
              const float* __restrict__ b_lin, const float* __restrict__ b_lin_reg,
              float* __restrict__ out)
{
    const int idx = blockIdx.x * 256 + threadIdx.x;   // 2*512*3072
    const int c = idx % 3072;
    const int r = (idx / 3072) & 511;
    const int g = idx / (3072 * 512);
    float v;
    if (c < 1024) {
        v = 0.f;
        #pragma unroll
        for (int s = 0; s < 8; ++s)
            v += avePart[(size_t)s * 1048576 + (size_t)g * 524288 + r * 1024 + c];
    } else {
        const int cc = c - 1024;
        v = (g ? b_lin_reg : b_lin)[cc];
        #pragma unroll
        for (int s = 0; s < 4; ++s)
            v += outPart[(size_t)s * 2097152 + (size_t)g * 1048576 + r * 2048 + cc];
    }
    out[idx] = v;
}

extern "C" void kernel_launch(void* const* d_in, const int* in_sizes, int n_in,
                              void* d_out, int out_size, void* d_ws, size_t ws_size,
                              hipStream_t stream)
{
    const float* x_cls     = (const float*)d_in[0];
    const float* x_reg     = (const float*)d_in[1];
    const float* cls_score = (const float*)d_in[2];
    const float* W_q_cls   = (const float*)d_in[4];
    const float* W_kv_cls  = (const float*)d_in[5];
    const float* W_q_reg   = (const float*)d_in[6];
    const float* W_kv_reg  = (const float*)d_in[7];
    const float* W_lin     = (const float*)d_in[8];
    const float* b_lin     = (const float*)d_in[9];
    const float* W_lin_reg = (const float*)d_in[10];
    const float* b_lin_reg = (const float*)d_in[11];
    float* out = (float*)d_out;

    if (ws_size < (size_t)122 * 1048576) return;

    // Workspace overlay (MiB offsets), peak 122 MiB. Region sizes:
    //   WlinT 16 | vT 8 | x_ori 2 | w_c 2 | w_r 2 | qn 2 | qpart16 16 |
    //   xbf 8 | WqT 4 | WkvT 8 | kvpart 32 | kn 8 | vn 8 (kn at 102..110,
    //   vn at 110..118 -- R7 bug was vn at 106 overlapping kn's upper half)
    char* W = (char*)d_ws;
    auto at = [&](size_t mb) { return (void*)(W + mb * 1048576); };
    _Float16* WlinT   = (_Float16*)at(0);    // prep -> out-lin            [0,16)
    _Float16* vT      = (_Float16*)at(16);   // vT_sum -> M3               [16,24)
    _Float16* x_ori   = (_Float16*)at(24);   // headnorm_kv -> build_xcat  [24,26)
    _Float16* w_c     = (_Float16*)at(26);   // sb2 -> M3                  [26,28)
    _Float16* w_r     = (_Float16*)at(28);   //                            [28,30)
    _Float16* qn      = (_Float16*)at(30);   // headnorm_q -> M2           [30,32)
    _Float16* qpart16 = (_Float16*)at(34);   // M1 -> headnorm_q           [34,50)
    _Float16* xbf     = (_Float16*)at(50);   // cast -> M1                 [50,58)
    _Float16* WqT     = (_Float16*)at(58);   // prep -> M1                 [58,62)
    _Float16* WkvT    = (_Float16*)at(62);   // prep -> M1                 [62,70)
    _Float16* kvpart  = (_Float16*)at(70);   // M1 -> norms/vT_sum         [70,102)
    _Float16* kn      = (_Float16*)at(102);  // headnorm_kv -> M2          [102,110)
    _Float16* vn      = (_Float16*)at(110);  // headnorm_kv -> M2          [110,118)
    _Float16* S16     = (_Float16*)at(34);   // M2 -> sb2                  [34,66)
    float*    simPart = (float*)at(70);      // M2 -> sb2 (kvpart dead)    [70,102)
    _Float16* attn_h  = (_Float16*)at(102);  // sb2 -> M3 (kn+vn dead)     [102,118)
    float*    xcatPart= (float*)at(34);      // M3 -> build_xcat (S16 dead)[34,66)
    float*    avePart = (float*)at(66);      // M3 -> finalize             [66,98)
    _Float16* xcat16  = (_Float16*)at(118);  // build_xcat -> out-lin      [118,122)
    float*    outPart = (float*)at(34);      // out-lin -> finalize        [34,66)

    // Phase 1: prep (2 launches)
    cast_f2h<<<dim3(2048, 2), 256, 0, stream>>>(x_cls, x_reg, xbf, 524288);
    prep_transpose<<<dim3(64, 64, 6), 256, 0, stream>>>(
        W_q_cls, W_q_reg, W_kv_cls, W_kv_reg, W_lin, W_lin_reg, WqT, WkvT, WlinT);

    // Phase 2 (M1): kv-proj (SK=2, fp16 partials) + q-proj (SK=8, fp16 partials)
    {
        GD kv = mkgd(xbf, WkvT, kvpart, nullptr,
                     0, 2097152, 0, 2097152, 8388608, 0, 4194304,
                     1024, 1024, 2048, 1024, 2, 0, 0, 0, 1, 0, 16, 16, 1.f);
        GD q  = mkgd(xbf, WqT, qpart16, nullptr,
                     0, 2097152, 0, 1048576, 1048576, 0, 524288,
                     1024, 1024, 1024, 1024, 8, 0, 0, 0, 1, 0, 8, 4, 1.f);
        hgemm2<<<dim3(16, 16, 20), 256, 0, stream>>>(kv, q, 4);
    }

    // Phase 3: norms + V^T (reduces fused)
    headnorm_q<<<2048, 256, 0, stream>>>(qpart16, qn);
    headnorm_kv<<<16384, 256, 0, stream>>>(kvpart, kn, vn, x_ori);
    vT_sum<<<dim3(32, 64, 2), 256, 0, stream>>>(kvpart, vT);

    // Phase 4 (M2): v-sim (SK=4, fp32 partials) + scores (z=16, fp16)
    {
        GD vs = mkgd(vn, vn, simPart, nullptr,
                     0, 2097152, 0, 2097152, 2097152, 0, 1048576,
                     1024, 1024, 2048, 1024, 4, 0, 0, 0, 0, 0, 16, 4, 0.125f);
        GD sc = mkgd(qn, kn, S16, cls_score,
                     128, 524288, 128, 2097152, 0, 1048576, 8388608,
                     1024, 1024, 2048, 128, 1, 7, 3, 0, 1, 2, 16, 4, 25.f);
        hgemm2<<<dim3(16, 4, 24), 256, 0, stream>>>(vs, sc, 8);
    }

    // Phase 5: fused dual softmax + blend + head-mean + round2 weights
    sb2_kernel<<<512, 256, 0, stream>>>(S16, simPart, attn_h, w_c, w_r);

    // Phase 6 (M3): attn@V (AHX, SK=8) + ave (SK=8), both fp32 partials
    {
        GD av = mkgd(attn_h, vT, xcatPart, nullptr,
                     1048576, 0, 0, 2097152, 1048576, 0, 524288,
                     2048, 2048, 1024, 2048, 8, 0, 0, 1, 0, 0, 8, 4, 1.f);
        GD ae = mkgd(w_c, vT, avePart, nullptr,
                     0, 1048576, 0, 2097152, 1048576, 0, 524288,
                     2048, 2048, 1024, 2048, 8, 0, 0, 0, 0, 0, 8, 4, 1.f);
        hgemm2<<<dim3(8, 4, 32), 256, 0, stream>>>(av, ae, 16);
    }

    // Phase 7: xcat assembly (8-way reduce + x_ori)
    build_xcat<<<8192, 256, 0, stream>>>(xcatPart, x_ori, xcat16);

    // Phase 8: out-linears (SK=4, fp32 partials)
    {
        GD ol = mkgd(xcat16, WlinT, outPart, nullptr,
                     0, 1048576, 0, 4194304, 2097152, 0, 1048576,
                     2048, 2048, 2048, 2048, 4, 0, 0, 0, 0, 0, 16, 4, 1.f);
        hgemm2<<<dim3(16, 4, 8), 256, 0, stream>>>(ol, ol, 8);
    }

    // Phase 9: write d_out
    finalize<<<12288, 256, 0, stream>>>(avePart, outPart, b_lin, b_lin_reg, out);
}

// Round 9
// 340.032 us; speedup vs baseline: 1.0611x; 1.0611x over previous
//
#include <hip/hip_runtime.h>

// Problem constants (B=1)
constexpr int kN1 = 512;
constexpr int kN2 = 2048;
constexpr int kC  = 1024;
constexpr int kHD = 128;
constexpr int kC2 = 2048;
constexpr int kC3 = 3072;

typedef _Float16 half8 __attribute__((ext_vector_type(8)));
typedef _Float16 half4v __attribute__((ext_vector_type(4)));
typedef float f32x4 __attribute__((ext_vector_type(4)));

// async global->LDS, 16 B per lane; LDS dest is wave-uniform base + lane*16
#define GLD16(gptr, lptr) \
    __builtin_amdgcn_global_load_lds((const __attribute__((address_space(1))) void*)(gptr), \
                                     (__attribute__((address_space(3))) void*)(lptr), 16, 0, 0)

// s_waitcnt immediates: vmcnt [3:0]|[15:14], expcnt [6:4], lgkmcnt [11:8]
#define WAIT_VM8   0x0F78  // vmcnt(8)
#define WAIT_VM0   0x0F70  // vmcnt(0)
#define WAIT_LGKM0 0xC07F  // lgkmcnt(0)

// ---------------------------------------------------------------------------
// GEMM descriptor (two independent GEMMs share one launch via blockIdx.z).
// zz = bz / SK; s = bz % SK; h = ahx ? blockIdx.x : zz & hmask;
// g = ahx ? zz : zz >> hshift.
// A += h*sAh + g*sAg; B += h*sBh + g*sBg; Coff = s*sSplit + h*sCh + g*sCg.
// In ahx mode, B-rows and C-cols get h implicitly through n0 (sBh=sCh=0).
// ---------------------------------------------------------------------------
struct GD {
    const _Float16* A; const _Float16* B; void* C;
    const float* colScale;
    long sAh, sAg, sBh, sBg, sSplit, sCh, sCg;
    int lda, ldb, ldc, K, SK, hmask, hshift;
    int ahx, outHalf, csMode, nx, ny;     // csMode: 0 none, 1 always, 2 g==0
    float alpha;
};

// Tile 128x128, BK=64 (2x16 MFMA between barrier pairs), 256 threads,
// 64 KB LDS double buffer. K/SK must be a multiple of 64.
__global__ __launch_bounds__(256)
void hgemm2(GD d0, GD d1, int zSplit)
{
    const bool second = (int)blockIdx.z >= zSplit;
    const GD& d = second ? d1 : d0;
    const int bz = second ? (int)blockIdx.z - zSplit : (int)blockIdx.z;
    if ((int)blockIdx.x >= d.nx || (int)blockIdx.y >= d.ny) return;

    __shared__ uint4 smem[4096];          // 64 KB: 2 x (A 16 KB | B 16 KB)
    char* smembase = (char*)smem;
    const int tid = threadIdx.x;
    const int w = tid >> 6, l = tid & 63;
    const int m0 = blockIdx.y << 7, n0 = blockIdx.x << 7;
    const int wm = (w >> 1) << 6, wn = (w & 1) << 6;
    const int kq = l >> 4, lm = l & 15;

    const int zz = bz / d.SK, s = bz - zz * d.SK;
    const int h = d.ahx ? (int)blockIdx.x : (zz & d.hmask);
    const int g = d.ahx ? zz : (zz >> d.hshift);
    const _Float16* A = d.A + (long)h * d.sAh + (long)g * d.sAg;
    const _Float16* B = d.B + (long)h * d.sBh + (long)g * d.sBg;
    const long Coff = (long)s * d.sSplit + (long)h * d.sCh + (long)g * d.sCg;
    const int kper = d.K / d.SK, kbeg = s * kper;
    const int nIter = kper >> 6;

    // staging: wave w covers LDS kq-chunks {w>>1, w>>1+2, +4, +6} for its
    // 64-row half; 8 GLD16 per iteration (4 A + 4 B).
    const int skq = w >> 1;
    const int sr0 = (w & 1) << 6;
    const _Float16* gA = A + (long)(m0 + sr0 + l) * d.lda + skq * 8 + kbeg;
    const _Float16* gB = B + (long)(n0 + sr0 + l) * d.ldb + skq * 8 + kbeg;
    const int soff = skq * 2048 + (sr0 + l) * 16;

    auto stage = [&](int it, int b) {
        char* dst = smembase + b * 32768;
        const int k0 = it << 6;
        GLD16(gA + k0,      dst + soff);
        GLD16(gA + k0 + 16, dst + soff + 4096);
        GLD16(gA + k0 + 32, dst + soff + 8192);
        GLD16(gA + k0 + 48, dst + soff + 12288);
        GLD16(gB + k0,      dst + 16384 + soff);
        GLD16(gB + k0 + 16, dst + 16384 + soff + 4096);
        GLD16(gB + k0 + 32, dst + 16384 + soff + 8192);
        GLD16(gB + k0 + 48, dst + 16384 + soff + 12288);
    };

    f32x4 acc[4][4] = {};
    stage(0, 0);

    for (int it = 0; it < nIter; ++it) {
        const int cur = it & 1;
        if (it + 1 < nIter) {
            stage(it + 1, cur ^ 1);
            __builtin_amdgcn_s_waitcnt(WAIT_VM8);   // current tile's 8 loads done
        } else {
            __builtin_amdgcn_s_waitcnt(WAIT_VM0);
        }
        __builtin_amdgcn_s_barrier();               // all waves' loads landed
        const char* cbase = smembase + cur * 32768;
        #pragma unroll
        for (int ks = 0; ks < 2; ++ks) {
            half8 af[4], bfr[4];
            const char* pa = cbase + ks * 8192 + kq * 2048 + (wm + lm) * 16;
            const char* pb = cbase + 16384 + ks * 8192 + kq * 2048 + (wn + lm) * 16;
            #pragma unroll
            for (int i = 0; i < 4; ++i) {
                af[i]  = *(const half8*)(pa + i * 256);
                bfr[i] = *(const half8*)(pb + i * 256);
            }
            #pragma unroll
            for (int mi = 0; mi < 4; ++mi)
                #pragma unroll
                for (int ni = 0; ni < 4; ++ni)
                    acc[mi][ni] = __builtin_amdgcn_mfma_f32_16x16x32_f16(af[mi], bfr[ni], acc[mi][ni], 0, 0, 0);
        }
        __builtin_amdgcn_s_waitcnt(WAIT_LGKM0);     // own ds_reads retired
        __builtin_amdgcn_s_barrier();               // all done reading cur
    }

    // C/D layout: col = lane&15, row = (lane>>4)*4 + reg
    const int rbase = m0 + wm + kq * 4;
    #pragma unroll
    for (int mi = 0; mi < 4; ++mi) {
        #pragma unroll
        for (int ni = 0; ni < 4; ++ni) {
            const int col = n0 + wn + ni * 16 + lm;
            float cs = d.alpha;
            if (d.csMode == 1 || (d.csMode == 2 && g == 0)) cs *= d.colScale[col];
            #pragma unroll
            for (int r = 0; r < 4; ++r) {
                const long row = rbase + mi * 16 + r;
                const float v = acc[mi][ni][r] * cs;
                const long off = Coff + row * d.ldc + col;
                if (d.outHalf) ((_Float16*)d.C)[off] = (_Float16)v;
                else           ((float*)d.C)[off] = v;
            }
        }
    }
}

static GD mkgd(const _Float16* A, const _Float16* B, void* C, const float* cscale,
               long sAh, long sAg, long sBh, long sBg, long sSplit, long sCh, long sCg,
               int lda, int ldb, int ldc, int K, int SK, int hmask, int hshift,
               int ahx, int outHalf, int csMode, int nx, int ny, float alpha)
{
    GD d; d.A=A; d.B=B; d.C=C; d.colScale=cscale;
    d.sAh=sAh; d.sAg=sAg; d.sBh=sBh; d.sBg=sBg; d.sSplit=sSplit; d.sCh=sCh; d.sCg=sCg;
    d.lda=lda; d.ldb=ldb; d.ldc=ldc; d.K=K; d.SK=SK; d.hmask=hmask; d.hshift=hshift;
    d.ahx=ahx; d.outHalf=outHalf; d.csMode=csMode; d.nx=nx; d.ny=ny; d.alpha=alpha;
    return d;
}

// ---------------------------------------------------------------------------
// fp32 -> fp16 cast, z picks (x_cls | x_reg) -> d[z]
// ---------------------------------------------------------------------------
__global__ __launch_bounds__(256)
void cast_f2h(const float* __restrict__ s0, const float* __restrict__ s1,
              _Float16* __restrict__ d, int n4)
{
    const int i = blockIdx.x * 256 + threadIdx.x;
    const float* s = blockIdx.y ? s1 : s0;
    const float4 v = ((const float4*)s)[i];
    half4v o;
    o.x = (_Float16)v.x; o.y = (_Float16)v.y; o.z = (_Float16)v.z; o.w = (_Float16)v.w;
    ((half4v*)(d + (size_t)blockIdx.y * n4 * 4))[i] = o;
}

// ---------------------------------------------------------------------------
// All six weight transposes in one launch. Grid (64,64,6); idle blocks exit.
// ---------------------------------------------------------------------------
__global__ __launch_bounds__(256)
void prep_transpose(const float* __restrict__ Wq_c, const float* __restrict__ Wq_r,
                    const float* __restrict__ Wkv_c, const float* __restrict__ Wkv_r,
                    const float* __restrict__ Wl_c, const float* __restrict__ Wl_r,
                    _Float16* __restrict__ WqT, _Float16* __restrict__ WkvT,
                    _Float16* __restrict__ WlinT)
{
    __shared__ float t[32][33];
    const int z = blockIdx.z;
    const float* src; _Float16* dst; int ldsrc, lddst, nx, ky;
    switch (z) {
        case 0: src=Wq_c;  dst=WqT;            ldsrc=1024; lddst=1024; nx=32; ky=32; break;
        case 1: src=Wq_r;  dst=WqT+1048576;    ldsrc=1024; lddst=1024; nx=32; ky=32; break;
        case 2: src=Wkv_c; dst=WkvT;           ldsrc=2048; lddst=1024; nx=64; ky=32; break;
        case 3: src=Wkv_r; dst=WkvT+2097152;   ldsrc=2048; lddst=1024; nx=64; ky=32; break;
        case 4: src=Wl_c;  dst=WlinT;          ldsrc=2048; lddst=2048; nx=64; ky=64; break;
        default:src=Wl_r;  dst=WlinT+4194304;  ldsrc=2048; lddst=2048; nx=64; ky=64; break;
    }
    if ((int)blockIdx.x >= nx || (int)blockIdx.y >= ky) return;
    const int n0 = blockIdx.x << 5, k0 = blockIdx.y << 5;
    const int tx = threadIdx.x & 31, ty = threadIdx.x >> 5;
    #pragma unroll
    for (int j = ty; j < 32; j += 8)
        t[j][tx] = src[(size_t)(k0 + j) * ldsrc + n0 + tx];
    __syncthreads();
    #pragma unroll
    for (int j = ty; j < 32; j += 8)
        dst[(size_t)(n0 + j) * lddst + k0 + tx] = (_Float16)t[tx][j];
}

// ---------------------------------------------------------------------------
// Phase-3 fused kernel: by blockIdx.x range —
//  [0,2048):        q-norm with 4-way split-K reduce (qpart16 [4][2][512][1024])
//  [2048,18432):    kv-norm from direct kvh [2][2048][2048] + x_ori emission
//  [18432,22528):   V^T: vT[g][n][k] = kvh[g][k][1024+n]
// ---------------------------------------------------------------------------
__global__ __launch_bounds__(256)
void phase3(const _Float16* __restrict__ qpart, const _Float16* __restrict__ kvh,
            _Float16* __restrict__ qn, _Float16* __restrict__ kn,
            _Float16* __restrict__ vn, _Float16* __restrict__ x_ori,
            _Float16* __restrict__ vT)
{
    __shared__ float t[32][33];
    const int b = blockIdx.x;
    if (b < 2048) {
        const int vid = b * 4 + (threadIdx.x >> 6);
        const int lane = threadIdx.x & 63;
        const int g = vid >> 12, rr = vid & 4095, row = rr >> 3, hh = rr & 7;
        const size_t o = (size_t)g * 524288 + (size_t)row * 1024 + hh * 128 + lane * 2;
        float a = 0.f, bb = 0.f;
        #pragma unroll
        for (int s = 0; s < 4; ++s) {
            a  += (float)qpart[(size_t)s * 1048576 + o];
            bb += (float)qpart[(size_t)s * 1048576 + o + 1];
        }
        float ss = a * a + bb * bb;
        #pragma unroll
        for (int d = 32; d > 0; d >>= 1) ss += __shfl_xor(ss, d, 64);
        const float inv = rsqrtf(ss);
        qn[o] = (_Float16)(a * inv); qn[o + 1] = (_Float16)(bb * inv);
    } else if (b < 18432) {
        const int vid = (b - 2048) * 4 + (threadIdx.x >> 6);   // [0, 65536)
        const int lane = threadIdx.x & 63;
        const int half_ = vid >> 15;            // 0 = K, 1 = V
        const int r15 = vid & 32767;
        const int g = r15 >> 14, rr = r15 & 16383, row = rr >> 3, hh = rr & 7;
        const size_t so = (size_t)g * 4194304 + (size_t)row * 2048
                        + half_ * 1024 + hh * 128 + lane * 2;
        const float a = (float)kvh[so], bb = (float)kvh[so + 1];
        float ss = a * a + bb * bb;
        #pragma unroll
        for (int d = 32; d > 0; d >>= 1) ss += __shfl_xor(ss, d, 64);
        const float inv = rsqrtf(ss);
        const size_t dofs = (size_t)g * 2097152 + (size_t)row * 1024 + hh * 128 + lane * 2;
        _Float16* dp = (half_ ? vn : kn) + dofs;
        dp[0] = (_Float16)(a * inv); dp[1] = (_Float16)(bb * inv);
        if (half_ == 1 && row < 512) {
            _Float16* xo = x_ori + (size_t)g * 524288 + (size_t)row * 1024 + hh * 128 + lane * 2;
            xo[0] = (_Float16)a; xo[1] = (_Float16)bb;
        }
    } else {
        const int vb = b - 18432;               // [0, 4096)
        const int g = vb >> 11, r = vb & 2047;
        const int n0 = (r & 31) << 5, k0 = (r >> 5) << 5;
        const int tx = threadIdx.x & 31, ty = threadIdx.x >> 5;
        const _Float16* s0 = kvh + (size_t)g * 4194304 + 1024;
        #pragma unroll
        for (int j = ty; j < 32; j += 8)
            t[j][tx] = (float)s0[(size_t)(k0 + j) * 2048 + n0 + tx];
        __syncthreads();
        _Float16* d = vT + (size_t)g * 2097152;
        #pragma unroll
        for (int j = ty; j < 32; j += 8)
            d[(size_t)(n0 + j) * 2048 + k0 + tx] = (_Float16)t[tx][j];
    }
}

// ---------------------------------------------------------------------------
// Block reduce (256 threads, 4 waves). OP: 0 sum, 1 max
// ---------------------------------------------------------------------------
template<int OP>
__device__ __forceinline__ float bred(float v, float* lds)
{
    #pragma unroll
    for (int o = 32; o > 0; o >>= 1) {
        const float u = __shfl_xor(v, o, 64);
        v = OP ? fmaxf(v, u) : v + u;
    }
    __syncthreads();
    if ((threadIdx.x & 63) == 0) lds[threadIdx.x >> 6] = v;
    __syncthreads();
    return OP ? fmaxf(fmaxf(lds[0], lds[1]), fmaxf(lds[2], lds[3]))
              : lds[0] + lds[1] + lds[2] + lds[3];
}

// ---------------------------------------------------------------------------
// Fused: per q row — dual softmax per head + blend -> fp16 attn + head-mean,
// then round-2 masked renorm weights. v-sim 2-way split-K reduced inline.
// S16 [16][512][2048] fp16 (0-7 cls, 8-15 reg); simPart [2][2][512][2048] f32.
// ---------------------------------------------------------------------------
__global__ __launch_bounds__(256)
void sb2_kernel(const _Float16* __restrict__ S16, const float* __restrict__ simPart,
                _Float16* __restrict__ attn,
                _Float16* __restrict__ wc, _Float16* __restrict__ wr)
{
    __shared__ float lds[4];
    const int q = blockIdx.x, t = threadIdx.x;
    float asum[8] = {};
    for (int hh = 0; hh < 8; ++hh) {
        const size_t rb = (size_t)(hh * 512 + q) * 2048;
        float vc[8], vr[8];
        float mc = -1e30f, mr = -1e30f;
        #pragma unroll
        for (int j = 0; j < 8; ++j) {
            vc[j] = (float)S16[rb + t + 256 * j];
            vr[j] = (float)S16[8388608 + rb + t + 256 * j];
            mc = fmaxf(mc, vc[j]); mr = fmaxf(mr, vr[j]);
        }
        mc = bred<1>(mc, lds);
        mr = bred<1>(mr, lds);
        float sc = 0.f, sr = 0.f;
        #pragma unroll
        for (int j = 0; j < 8; ++j) {
            vc[j] = expf(vc[j] - mc); sc += vc[j];
            vr[j] = expf(vr[j] - mr); sr += vr[j];
        }
        sc = bred<0>(sc, lds);
        sr = bred<0>(sr, lds);
        const float ic = 0.5f / sc, ir = 0.5f / sr;
        #pragma unroll
        for (int j = 0; j < 8; ++j) {
            const float a = vc[j] * ic + vr[j] * ir;
            attn[rb + t + 256 * j] = (_Float16)a;
            asum[j] += a;
        }
    }
    float mx = -1e30f;
    #pragma unroll
    for (int j = 0; j < 8; ++j) { asum[j] *= 0.125f; mx = fmaxf(mx, asum[j]); }
    mx = bred<1>(mx, lds);
    float em[8], emo[8];
    float s1 = 0.f, s2 = 0.f;
    const size_t qb = (size_t)q * 2048;
    #pragma unroll
    for (int j = 0; j < 8; ++j) {
        const size_t o = qb + t + 256 * j;
        const float sim = simPart[o] + simPart[2097152 + o];
        const float reg = simPart[1048576 + o] + simPart[3145728 + o];
        const float e = expf(asum[j] - mx);
        const float m  = sim > 0.75f ? 1.f : 0.f;
        const float mo = reg > 0.99f ? 1.f : 0.f;
        em[j] = e * m; emo[j] = e * m * mo;
        s1 += em[j]; s2 += emo[j];
    }
    s1 = bred<0>(s1, lds);
    s2 = bred<0>(s2, lds);
    const float i1 = 1.f / s1, i2 = 1.f / s2;
    #pragma unroll
    for (int j = 0; j < 8; ++j) {
        wc[qb + t + 256 * j] = (_Float16)(em[j] * i1);
        wr[qb + t + 256 * j] = (_Float16)(emo[j] * i2);
    }
}

// ---------------------------------------------------------------------------
// xcat16 [2][512][2048]: cols<1024 = 4-way reduce of attn@V partials,
// cols>=1024 = x_ori.
// ---------------------------------------------------------------------------
__global__ __launch_bounds__(256)
void build_xcat(const float* __restrict__ xcatPart, const _Float16* __restrict__ x_ori,
                _Float16* __restrict__ xcat)
{
    const int idx = blockIdx.x * 256 + threadIdx.x;   // 2*512*2048
    const int j = idx & 2047;
    const int n = (idx >> 11) & 511;
    const int g = idx >> 20;
    _Float16 v;
    if (j < 1024) {
        float a = 0.f;
        #pragma unroll
        for (int s = 0; s < 4; ++s)
            a += xcatPart[(size_t)s * 1048576 + (size_t)g * 524288 + n * 1024 + j];
        v = (_Float16)a;
    } else {
        v = x_ori[(size_t)g * 524288 + (size_t)n * 1024 + (j - 1024)];
    }
    xcat[idx] = v;
}

// ---------------------------------------------------------------------------
// finalize d_out [2][512][3072]: cols<1024 4-way avePart reduce; cols>=1024
// 4-way outPart reduce + bias.
// ---------------------------------------------------------------------------
__global__ __launch_bounds__(256)
void finalize(const float* __restrict__ avePart, const float* __restrict__ outPart,
              const float* __restrict__ b_lin, const float* __restrict__ b_lin_reg,
              float* __restrict__ out)
{
    const int idx = blockIdx.x * 256 + threadIdx.x;   // 2*512*3072
    const int c = idx % 3072;
    const int r = (idx / 3072) & 511;
    const int g = idx / (3072 * 512);
    float v;
    if (c < 1024) {
        v = 0.f;
        #pragma unroll
        for (int s = 0; s < 4; ++s)
            v += avePart[(size_t)s * 1048576 + (size_t)g * 524288 + r * 1024 + c];
    } else {
        const int cc = c - 1024;
        v = (g ? b_lin_reg : b_lin)[cc];
        #pragma unroll
        for (int s = 0; s < 4; ++s)
            v += outPart[(size_t)s * 2097152 + (size_t)g * 1048576 + r * 2048 + cc];
    }
    out[idx] = v;
}

extern "C" void kernel_launch(void* const* d_in, const int* in_sizes, int n_in,
                              void* d_out, int out_size, void* d_ws, size_t ws_size,
                              hipStream_t stream)
{
    const float* x_cls     = (const float*)d_in[0];
    const float* x_reg     = (const float*)d_in[1];
    const float* cls_score = (const float*)d_in[2];
    const float* W_q_cls   = (const float*)d_in[4];
    const float* W_kv_cls  = (const float*)d_in[5];
    const float* W_q_reg   = (const float*)d_in[6];
    const float* W_kv_reg  = (const float*)d_in[7];
    const float* W_lin     = (const float*)d_in[8];
    const float* b_lin     = (const float*)d_in[9];
    const float* W_lin_reg = (const float*)d_in[10];
    const float* b_lin_reg = (const float*)d_in[11];
    float* out = (float*)d_out;

    if (ws_size < (size_t)124 * 1048576) return;

    // Workspace overlay (MiB offsets), peak 124 MiB:
    char* W = (char*)d_ws;
    auto at = [&](size_t mb) { return (void*)(W + mb * 1048576); };
    _Float16* WlinT   = (_Float16*)at(0);    // prep -> out-lin            [0,16)
    _Float16* vT      = (_Float16*)at(16);   // phase3 -> M3               [16,24)
    _Float16* x_ori   = (_Float16*)at(24);   // phase3 -> build_xcat       [24,26)
    _Float16* w_c     = (_Float16*)at(26);   // sb2 -> M3                  [26,28)
    _Float16* w_r     = (_Float16*)at(28);   //                            [28,30)
    _Float16* qn      = (_Float16*)at(30);   // phase3 -> M2               [30,32)
    _Float16* kvh     = (_Float16*)at(32);   // M1 -> phase3               [32,48)
    float*    simPart = (float*)at(32);      // M2 -> sb2 (kvh dead)       [32,48)
    _Float16* qpart16 = (_Float16*)at(48);   // M1 -> phase3               [48,56)
    _Float16* xcat16  = (_Float16*)at(48);   // build_xcat -> out-lin      [48,52)
    _Float16* xbf     = (_Float16*)at(56);   // cast -> M1                 [56,64)
    _Float16* WqT     = (_Float16*)at(64);   // prep -> M1                 [64,68)
    _Float16* WkvT    = (_Float16*)at(68);   // prep -> M1                 [68,76)
    _Float16* kn      = (_Float16*)at(76);   // phase3 -> M2               [76,84)
    _Float16* vn      = (_Float16*)at(84);   // phase3 -> M2               [84,92)
    _Float16* attn_h  = (_Float16*)at(76);   // sb2 -> M3 (kn/vn dead)     [76,92)
    float*    outPart = (float*)at(56);      // out-lin -> finalize        [56,88)
    _Float16* S16     = (_Float16*)at(92);   // M2 -> sb2                  [92,124)
    float*    xcatPart= (float*)at(92);      // M3 -> build_xcat (S16 dead)[92,108)
    float*    avePart = (float*)at(108);     // M3 -> finalize             [108,124)

    // Phase 1: prep
    cast_f2h<<<dim3(2048, 2), 256, 0, stream>>>(x_cls, x_reg, xbf, 524288);
    prep_transpose<<<dim3(64, 64, 6), 256, 0, stream>>>(
        W_q_cls, W_q_reg, W_kv_cls, W_kv_reg, W_lin, W_lin_reg, WqT, WkvT, WlinT);

    // Phase 2 (M1): kv-proj (direct fp16, z=2) + q-proj (SK=4, fp16 partials)
    {
        GD kv = mkgd(xbf, WkvT, kvh, nullptr,
                     0, 2097152, 0, 2097152, 0, 0, 4194304,
                     1024, 1024, 2048, 1024, 1, 0, 0, 0, 1, 0, 16, 16, 1.f);
        GD q  = mkgd(xbf, WqT, qpart16, nullptr,
                     0, 2097152, 0, 1048576, 1048576, 0, 524288,
                     1024, 1024, 1024, 1024, 4, 0, 0, 0, 1, 0, 8, 4, 1.f);
        hgemm2<<<dim3(16, 16, 10), 256, 0, stream>>>(kv, q, 2);
    }

    // Phase 3: fused norms + V^T
    phase3<<<22528, 256, 0, stream>>>(qpart16, kvh, qn, kn, vn, x_ori, vT);

    // Phase 4 (M2): v-sim (SK=2, fp32 partials) + scores (z=16, fp16)
    {
        GD vs = mkgd(vn, vn, simPart, nullptr,
                     0, 2097152, 0, 2097152, 2097152, 0, 1048576,
                     1024, 1024, 2048, 1024, 2, 0, 0, 0, 0, 0, 16, 4, 0.125f);
        GD sc = mkgd(qn, kn, S16, cls_score,
                     128, 524288, 128, 2097152, 0, 1048576, 8388608,
                     1024, 1024, 2048, 128, 1, 7, 3, 0, 1, 2, 16, 4, 25.f);
        hgemm2<<<dim3(16, 4, 20), 256, 0, stream>>>(vs, sc, 4);
    }

    // Phase 5: fused dual softmax + blend + head-mean + round2 weights
    sb2_kernel<<<512, 256, 0, stream>>>(S16, simPart, attn_h, w_c, w_r);

    // Phase 6 (M3): attn@V (AHX, SK=4) + ave (SK=4), both fp32 partials
    {
        GD av = mkgd(attn_h, vT, xcatPart, nullptr,
                     1048576, 0, 0, 2097152, 1048576, 0, 524288,
                     2048, 2048, 1024, 2048, 4, 0, 0, 1, 0, 0, 8, 4, 1.f);
        GD ae = mkgd(w_c, vT, avePart, nullptr,
                     0, 1048576, 0, 2097152, 1048576, 0, 524288,
                     2048, 2048, 1024, 2048, 4, 0, 0, 0, 0, 0, 8, 4, 1.f);
        hgemm2<<<dim3(8, 4, 16), 256, 0, stream>>>(av, ae, 8);
    }

    // Phase 7: xcat assembly (4-way reduce + x_ori)
    build_xcat<<<8192, 256, 0, stream>>>(xcatPart, x_ori, xcat16);

    // Phase 8: out-linears (SK=4, fp32 partials)
    {
        GD ol = mkgd(xcat16, WlinT, outPart, nullptr,
                     0, 1048576, 0, 4194304, 2097152, 0, 1048576,
                     2048, 2048, 2048, 2048, 4, 0, 0, 0, 0, 0, 16, 4, 1.f);
        hgemm2<<<dim3(16, 4, 8), 256, 0, stream>>>(ol, ol, 8);
    }

    // Phase 9: write d_out
    finalize<<<12288, 256, 0, stream>>>(avePart, outPart, b_lin, b_lin_reg, out);
}